// Round 6
// baseline (86.294 us; speedup 1.0000x reference)
//
#include <hip/hip_runtime.h>

#define N_ATOMS  4096
#define N_RBF    16
#define N_HIDDEN 64
#define NTHREADS 1024
#define WPB      16                // waves per block
#define APB      8                 // atoms per block (2 waves per atom)
#define NBLOCKS  (N_ATOMS / APB)   // 512 blocks -> 2/CU, 32 waves/CU
#define QCAP     192               // per-wave (half-space) candidate queue
#define HALF_J   (N_ATOMS / 2)     // 2048

__global__ void zero_out_kernel(float* __restrict__ out) {
    if (threadIdx.x == 0 && blockIdx.x == 0) out[0] = 0.0f;
}

// One pair's RBF contribution into f[0..15]. d2=1e8 sentinel -> exactly 0.
__device__ __forceinline__ void accum_rbf(float d2, float (&f)[N_RBF]) {
    const float d  = sqrtf(d2);
    const float sm = 0.5f + 0.5f * __cosf(0.62831853071795865f * d); // 0.5*(1+cos(pi*d/5))
    #pragma unroll
    for (int k = 0; k < N_RBF; ++k) {
        const float t = d - (0.5f + 0.3f * (float)k);   // centers 0.5+0.3k
        f[k] += sm * __expf(-20.48f * t * t);           // 1/(2*eta^2) = 20.48
    }
}

__device__ __forceinline__ int wave_prefix(unsigned long long m) {
    return __builtin_amdgcn_mbcnt_hi((unsigned)(m >> 32),
            __builtin_amdgcn_mbcnt_lo((unsigned)m, 0u));
}

// launch_bounds(1024, 8): 8 waves/EU min -> VGPR capped at 64 -> 32 waves/CU.
__global__ __launch_bounds__(NTHREADS, 8) void fused_sr_kernel(
    const float* __restrict__ pos,   // (N,3)
    const float* __restrict__ W1,    // (16,64)
    const float* __restrict__ b1,    // (64,)
    const float* __restrict__ W2,    // (64,64)
    const float* __restrict__ b2,    // (64,)
    const float* __restrict__ W3,    // (64,1)
    const float* __restrict__ b3,    // (1,)
    float* __restrict__ out)         // scalar
{
    __shared__ __align__(16) float4 sp[N_ATOMS];     // 64 KB
    __shared__ __align__(16) float qd[WPB][QCAP];    // 12 KB; rows reused as h1buf later
    __shared__ float pairbuf[APB][2][N_RBF];         // 1 KB
    __shared__ float ered[APB];
    // total ~77.3 KB -> 2 blocks/CU (154.6 of 160 KB)

    const int tid = threadIdx.x;

    for (int idx = tid; idx < N_ATOMS; idx += NTHREADS) {
        sp[idx] = make_float4(pos[idx * 3 + 0], pos[idx * 3 + 1], pos[idx * 3 + 2], 0.0f);
    }
    __syncthreads();

    const int lane = tid & 63;
    const int wib  = tid >> 6;
    const int pid  = wib >> 1;          // atom slot in block
    const int half = wib & 1;           // which j-half this wave sweeps
    const int i    = blockIdx.x * APB + pid;

    const float4 pi4 = sp[i];           // wave-uniform
    const float xi = pi4.x, yi = pi4.y, zi = pi4.z;

    // ---- branch-free compaction sweep over this wave's j-half ----
    int cnt = 0;
    const int jbase = half * HALF_J;
    #pragma unroll 4
    for (int j0 = 0; j0 < HALF_J; j0 += 64) {
        const float4 pj = sp[jbase + j0 + lane];
        const float dx = xi - pj.x;
        const float dy = yi - pj.y;
        const float dz = zi - pj.z;
        const float d2 = fmaf(dx, dx, fmaf(dy, dy, dz * dz));
        const bool act = (d2 < 25.0f) && (d2 > 1e-12f);  // 1e-6 < d < 5
        const unsigned long long m = __ballot(act);
        int widx = cnt + wave_prefix(m);
        widx = widx < QCAP ? widx : QCAP - 1;            // overflow clamp (safety)
        if (act) qd[wib][widx] = d2;                     // predicated, stride-1
        cnt += (int)__popcll(m);
    }

    // ---- drain: full-lane RBF evaluation (f live only from here) ----
    float f[N_RBF];
    #pragma unroll
    for (int k = 0; k < N_RBF; ++k) f[k] = 0.0f;
    for (int b = 0; b < cnt; b += 64) {
        const int q = b + lane;
        accum_rbf((q < cnt) ? qd[wib][q] : 1e8f, f);
    }

    // ---- butterfly allreduce of 16 half-space feature partials ----
    #pragma unroll
    for (int k = 0; k < N_RBF; ++k) {
        #pragma unroll
        for (int off = 32; off > 0; off >>= 1)
            f[k] += __shfl_xor(f[k], off, 64);
    }

    // Publish this wave's partial (static unroll; values are wave-uniform).
    if (lane == 0) {
        #pragma unroll
        for (int k = 0; k < N_RBF; ++k) pairbuf[pid][half][k] = f[k];
    }
    __syncthreads();   // partials visible; also: all queues now dead

    // ---- even wave of each pair runs the MLP for its atom ----
    if (half == 0) {
        float a1 = b1[lane];
        #pragma unroll
        for (int k = 0; k < N_RBF; ++k)
            a1 = fmaf(f[k] + pairbuf[pid][1][k], W1[k * N_HIDDEN + lane], a1);
        const float h1 = a1 / (1.0f + __expf(-a1));   // silu

        float* h1p = &qd[pid][0];       // reuse dead queue row (16B aligned)
        h1p[lane] = h1;                  // same-wave LDS exchange (DS in-order)
        float a2 = b2[lane];
        #pragma unroll
        for (int k = 0; k < N_HIDDEN; k += 4) {
            const float4 hv = *reinterpret_cast<const float4*>(&h1p[k]);
            a2 = fmaf(hv.x, W2[(k + 0) * N_HIDDEN + lane], a2);
            a2 = fmaf(hv.y, W2[(k + 1) * N_HIDDEN + lane], a2);
            a2 = fmaf(hv.z, W2[(k + 2) * N_HIDDEN + lane], a2);
            a2 = fmaf(hv.w, W2[(k + 3) * N_HIDDEN + lane], a2);
        }
        const float h2 = a2 / (1.0f + __expf(-a2));   // silu

        float e = h2 * W3[lane];
        #pragma unroll
        for (int off = 32; off > 0; off >>= 1)
            e += __shfl_xor(e, off, 64);
        if (lane == 0) ered[pid] = e;
    }
    __syncthreads();
    if (tid == 0) {
        float acc = 0.0f;
        #pragma unroll
        for (int w = 0; w < APB; ++w) acc += ered[w];
        atomicAdd(out, acc + (float)APB * b3[0]);
    }
}

extern "C" void kernel_launch(void* const* d_in, const int* in_sizes, int n_in,
                              void* d_out, int out_size, void* d_ws, size_t ws_size,
                              hipStream_t stream) {
    const float* pos = (const float*)d_in[0];
    const float* W1  = (const float*)d_in[1];
    const float* b1  = (const float*)d_in[2];
    const float* W2  = (const float*)d_in[3];
    const float* b2  = (const float*)d_in[4];
    const float* W3  = (const float*)d_in[5];
    const float* b3  = (const float*)d_in[6];
    float* out = (float*)d_out;

    zero_out_kernel<<<1, 64, 0, stream>>>(out);
    fused_sr_kernel<<<NBLOCKS, NTHREADS, 0, stream>>>(pos, W1, b1, W2, b2, W3, b3, out);
}

// Round 7
// 79.915 us; speedup vs baseline: 1.0798x; 1.0798x over previous
//
#include <hip/hip_runtime.h>

#define N_ATOMS  4096
#define N_RBF    16
#define N_HIDDEN 64
#define NTHREADS 1024
#define WPB      16                 // waves per block
#define APB      16                 // atoms per block (2 per wave-team)
#define NBLOCKS  (N_ATOMS / APB)    // 256 -> exactly 1 block per CU
#define QCAP     192                // per (atom, half) candidate queue
#define HALF_J   (N_ATOMS / 2)      // 2048

__global__ void zero_out_kernel(float* __restrict__ out) {
    if (threadIdx.x == 0 && blockIdx.x == 0) out[0] = 0.0f;
}

// One pair's RBF contribution into f[0..15]. d2=1e8 sentinel -> exactly 0.
__device__ __forceinline__ void accum_rbf(float d2, float (&f)[N_RBF]) {
    const float d  = sqrtf(d2);
    const float sm = 0.5f + 0.5f * __cosf(0.62831853071795865f * d); // 0.5*(1+cos(pi*d/5))
    #pragma unroll
    for (int k = 0; k < N_RBF; ++k) {
        const float t = d - (0.5f + 0.3f * (float)k);   // centers 0.5+0.3k
        f[k] += sm * __expf(-20.48f * t * t);           // 1/(2*eta^2) = 20.48
    }
}

__device__ __forceinline__ int wave_prefix(unsigned long long m) {
    return __builtin_amdgcn_mbcnt_hi((unsigned)(m >> 32),
            __builtin_amdgcn_mbcnt_lo((unsigned)m, 0u));
}

// No min-waves arg: 1024-thr block forces VGPR<=128 without spill pressure (R6 lesson).
__global__ __launch_bounds__(NTHREADS) void fused_sr_kernel(
    const float* __restrict__ pos,   // (N,3)
    const float* __restrict__ W1,    // (16,64)
    const float* __restrict__ b1,    // (64,)
    const float* __restrict__ W2,    // (64,64)
    const float* __restrict__ b2,    // (64,)
    const float* __restrict__ W3,    // (64,1)
    const float* __restrict__ b3,    // (1,)
    float* __restrict__ out)         // scalar
{
    __shared__ __align__(16) float4 sp[N_ATOMS];          // 64 KB
    __shared__ __align__(16) float  qd[APB][2][QCAP];     // 24 KB, per-ATOM rows
    __shared__ int qcnt[APB][2];
    __shared__ __align__(16) float  h1buf[WPB][N_HIDDEN]; // 4 KB
    __shared__ float ered[WPB];
    // ~92.3 KB -> 1 block/CU, 16 waves/CU (4/SIMD)

    const int tid = threadIdx.x;

    for (int idx = tid; idx < N_ATOMS; idx += NTHREADS) {
        sp[idx] = make_float4(pos[idx * 3 + 0], pos[idx * 3 + 1], pos[idx * 3 + 2], 0.0f);
    }
    __syncthreads();

    const int lane = tid & 63;
    const int w    = tid >> 6;
    const int t    = w >> 1;            // team (2 waves)
    const int h    = w & 1;             // j-half this wave sweeps
    const int iA   = blockIdx.x * APB + 2 * t;   // team's atoms: iA, iA+1

    const float4 pa = sp[iA];
    const float4 pb = sp[iA + 1];
    const int jbase = h * HALF_J;

    // ---- sweep this j-half for BOTH atoms: one ds_read_b128 feeds 2 tests ----
    int cntA = 0, cntB = 0;
    #pragma unroll 4
    for (int j0 = 0; j0 < HALF_J; j0 += 64) {
        const float4 pj = sp[jbase + j0 + lane];
        {   // atom A -> qd[2t+0][h]
            const float dx = pa.x - pj.x, dy = pa.y - pj.y, dz = pa.z - pj.z;
            const float d2 = fmaf(dx, dx, fmaf(dy, dy, dz * dz));
            const bool act = (d2 < 25.0f) && (d2 > 1e-12f);
            const unsigned long long m = __ballot(act);
            int widx = cntA + wave_prefix(m);
            widx = widx < QCAP ? widx : QCAP - 1;
            if (act) qd[2 * t + 0][h][widx] = d2;
            cntA += (int)__popcll(m);
        }
        {   // atom B -> qd[2t+1][h]
            const float dx = pb.x - pj.x, dy = pb.y - pj.y, dz = pb.z - pj.z;
            const float d2 = fmaf(dx, dx, fmaf(dy, dy, dz * dz));
            const bool act = (d2 < 25.0f) && (d2 > 1e-12f);
            const unsigned long long m = __ballot(act);
            int widx = cntB + wave_prefix(m);
            widx = widx < QCAP ? widx : QCAP - 1;
            if (act) qd[2 * t + 1][h][widx] = d2;
            cntB += (int)__popcll(m);
        }
    }
    if (lane == 0) { qcnt[2 * t + 0][h] = cntA; qcnt[2 * t + 1][h] = cntB; }
    __syncthreads();
    // Handoff: wave (t,h) now EXCLUSIVELY owns atom aloc = 2t+h (both its half-queues).

    const int aloc = 2 * t + h;
    const int ia   = blockIdx.x * APB + aloc;
    (void)ia;

    float f[N_RBF];
    #pragma unroll
    for (int k = 0; k < N_RBF; ++k) f[k] = 0.0f;
    #pragma unroll
    for (int part = 0; part < 2; ++part) {
        const int c = qcnt[aloc][part];
        for (int b = 0; b < c; b += 64) {
            const int q = b + lane;
            accum_rbf((q < c) ? qd[aloc][part][q] : 1e8f, f);
        }
    }

    // ---- allreduce of f[16] over 64 lanes: 2 xor folds + LDS transpose finish ----
    #pragma unroll
    for (int k = 0; k < N_RBF; ++k) {
        f[k] += __shfl_xor(f[k], 32, 64);
        f[k] += __shfl_xor(f[k], 16, 64);   // lane l now holds s_{l&15}[k] (4-lane group sum)
    }
    float* tb = &qd[aloc][0][0];   // 384-float wave-exclusive scratch (queues dead)
    if (lane < 16) {
        #pragma unroll
        for (int j = 0; j < 16; j += 4)
            *reinterpret_cast<float4*>(&tb[lane * 16 + j]) =
                make_float4(f[j], f[j + 1], f[j + 2], f[j + 3]);
    }
    // same-wave DS ordering: writes above complete before reads below
    const int kk = lane & 15, rep = lane >> 4;
    float F = 0.0f;
    #pragma unroll
    for (int i = 0; i < 4; ++i) F += tb[(4 * rep + i) * 16 + kk];
    F += __shfl_xor(F, 16, 64);
    F += __shfl_xor(F, 32, 64);            // F = full sum for k=lane&15, all reps
    if (lane < 16) tb[256 + lane] = F;
    float Fb[N_RBF];
    #pragma unroll
    for (int j = 0; j < 16; j += 4) {
        const float4 v = *reinterpret_cast<const float4*>(&tb[256 + j]);
        Fb[j] = v.x; Fb[j + 1] = v.y; Fb[j + 2] = v.z; Fb[j + 3] = v.w;
    }

    // ---- MLP for this wave's atom: lane h <-> hidden unit ----
    float a1 = b1[lane];
    #pragma unroll
    for (int k = 0; k < N_RBF; ++k)
        a1 = fmaf(Fb[k], W1[k * N_HIDDEN + lane], a1);
    const float h1 = a1 / (1.0f + __expf(-a1));   // silu

    h1buf[w][lane] = h1;   // same-wave LDS exchange
    float a2 = b2[lane];
    #pragma unroll
    for (int k = 0; k < N_HIDDEN; k += 4) {
        const float4 hv = *reinterpret_cast<const float4*>(&h1buf[w][k]);
        a2 = fmaf(hv.x, W2[(k + 0) * N_HIDDEN + lane], a2);
        a2 = fmaf(hv.y, W2[(k + 1) * N_HIDDEN + lane], a2);
        a2 = fmaf(hv.z, W2[(k + 2) * N_HIDDEN + lane], a2);
        a2 = fmaf(hv.w, W2[(k + 3) * N_HIDDEN + lane], a2);
    }
    const float h2 = a2 / (1.0f + __expf(-a2));   // silu

    float e = h2 * W3[lane];
    #pragma unroll
    for (int off = 32; off > 0; off >>= 1)
        e += __shfl_xor(e, off, 64);
    if (lane == 0) ered[w] = e;
    __syncthreads();
    if (tid == 0) {
        float acc = 0.0f;
        #pragma unroll
        for (int v = 0; v < WPB; ++v) acc += ered[v];
        atomicAdd(out, acc + (float)APB * b3[0]);
    }
}

extern "C" void kernel_launch(void* const* d_in, const int* in_sizes, int n_in,
                              void* d_out, int out_size, void* d_ws, size_t ws_size,
                              hipStream_t stream) {
    const float* pos = (const float*)d_in[0];
    const float* W1  = (const float*)d_in[1];
    const float* b1  = (const float*)d_in[2];
    const float* W2  = (const float*)d_in[3];
    const float* b2  = (const float*)d_in[4];
    const float* W3  = (const float*)d_in[5];
    const float* b3  = (const float*)d_in[6];
    float* out = (float*)d_out;

    zero_out_kernel<<<1, 64, 0, stream>>>(out);
    fused_sr_kernel<<<NBLOCKS, NTHREADS, 0, stream>>>(pos, W1, b1, W2, b2, W3, b3, out);
}